// Round 2
// 474.182 us; speedup vs baseline: 1.0122x; 1.0122x over previous
//
#include <hip/hip_runtime.h>
#include <math.h>

#define HH    768
#define QL    20
#define SS    512
#define DD    492
#define NBATCH 16
#define NLAYER 13
#define NBINS 11
#define DSPLIT 4
#define BROWS 123          // real d-rows per block
#define BN    128          // padded d-rows
#define BK    64
#define NKT   (HH / BK)    // 12 k-tiles
#define BPAD  72           // LDS row length in bf16 (64 + 8 pad)

typedef __attribute__((ext_vector_type(8))) short bf16x8;
typedef __attribute__((ext_vector_type(4))) float f32x4;

__device__ inline unsigned int pk2bf(float a, float b) {
    unsigned int ua = __float_as_uint(a);
    unsigned int ub = __float_as_uint(b);
    ua = (ua + 0x7fffu + ((ua >> 16) & 1u)) >> 16;   // RNE truncate
    ub = (ub + 0x7fffu + ((ub >> 16) & 1u)) >> 16;
    return ua | (ub << 16);
}

// Grid (13,16,4), 256 threads (4 waves). Per block: C(20x123) = Q(20x768)·Dchunk^T
// via mfma_f32_16x16x32_bf16, fp32 norms, fused histogram. Partial counts -> ws.
// v2: per-kt Q tiling (LDS 68.5->47.3 KB => 3 blocks/CU), double-buffered LDS with
// 1-deep register prefetch, ONE barrier per k-tile, register-accumulated norms.
__global__ __launch_bounds__(256, 3)
void gemm_hist_kernel(const float* __restrict__ hs, float* __restrict__ counts) {
    const int l = blockIdx.x, b = blockIdx.y, dc = blockIdx.z;
    const float* __restrict__ base = hs + (size_t)(l * NBATCH + b) * SS * HH;
    const int t = threadIdx.x;
    const int wave = t >> 6, lane = t & 63;
    const int quad = lane >> 4, m16 = lane & 15;

    __shared__ unsigned short sQ[2][32][BPAD];   // 9.2 KB  (rows 20..31 zero)
    __shared__ unsigned short sB[2][BN][BPAD];   // 36.9 KB
    __shared__ float s_qn2[QL], s_qn[QL];
    __shared__ float s_dn2[BN], s_dn[BN];
    __shared__ int   s_hist[NBINS];

    // ---- one-time init ----
    if (t < QL) s_qn2[t] = 0.f;
    if (t < BN) s_dn2[t] = 0.f;
    if (t < NBINS) s_hist[t] = 0;
    for (int i = t; i < 2 * 12 * BPAD; i += 256) {   // zero sQ pad rows (both bufs)
        int bufi = i / (12 * BPAD);
        int rem  = i - bufi * (12 * BPAD);
        sQ[bufi][20 + rem / BPAD][rem % BPAD] = 0;
    }

    // ---- fixed per-thread staging geometry (column advances with kt) ----
    const int  kf  = t & 15;            // float4-column within k-tile
    const int  qr0 = t >> 4;            // Q rows 0..15 (all threads)
    const bool q1  = (t < 64);          // wave 0 also stages Q rows 16..19
    const int  qr1 = 16 + (t >> 4);
    const int  rb  = t >> 4;            // B rows rb + 16j
    int  growB[8];
    bool bvld[8];
    #pragma unroll
    for (int j = 0; j < 8; ++j) {
        int row  = rb + 16 * j;
        bvld[j]  = (row < BROWS);
        growB[j] = QL + dc * BROWS + (row < BROWS ? row : BROWS - 1);
    }

    float qn0 = 0.f, qn1 = 0.f;
    float dnacc[8];
    #pragma unroll
    for (int j = 0; j < 8; ++j) dnacc[j] = 0.f;
    f32x4 acc[2][2] = {{{0,0,0,0},{0,0,0,0}},{{0,0,0,0},{0,0,0,0}}};

    // ---- prologue: load k-tile 0, convert+write buffer 0 ----
    {
        float4 pq0, pq1, pb[8];
        pq0 = *reinterpret_cast<const float4*>(base + qr0 * HH + kf * 4);
        if (q1) pq1 = *reinterpret_cast<const float4*>(base + qr1 * HH + kf * 4);
        #pragma unroll
        for (int j = 0; j < 8; ++j) {
            float4 z = {0.f, 0.f, 0.f, 0.f};
            pb[j] = bvld[j] ? *reinterpret_cast<const float4*>(base + (size_t)growB[j] * HH + kf * 4) : z;
        }
        qn0 += pq0.x*pq0.x + pq0.y*pq0.y + pq0.z*pq0.z + pq0.w*pq0.w;
        uint2 hw;
        hw.x = pk2bf(pq0.x, pq0.y); hw.y = pk2bf(pq0.z, pq0.w);
        *reinterpret_cast<uint2*>(&sQ[0][qr0][kf * 4]) = hw;
        if (q1) {
            qn1 += pq1.x*pq1.x + pq1.y*pq1.y + pq1.z*pq1.z + pq1.w*pq1.w;
            hw.x = pk2bf(pq1.x, pq1.y); hw.y = pk2bf(pq1.z, pq1.w);
            *reinterpret_cast<uint2*>(&sQ[0][qr1][kf * 4]) = hw;
        }
        #pragma unroll
        for (int j = 0; j < 8; ++j) {
            dnacc[j] += pb[j].x*pb[j].x + pb[j].y*pb[j].y + pb[j].z*pb[j].z + pb[j].w*pb[j].w;
            uint2 w2;
            w2.x = pk2bf(pb[j].x, pb[j].y); w2.y = pk2bf(pb[j].z, pb[j].w);
            *reinterpret_cast<uint2*>(&sB[0][rb + 16 * j][kf * 4]) = w2;
        }
    }
    __syncthreads();

    // ---- main loop: one barrier per k-tile; prefetch kt+1 over MFMA(kt) ----
    int cur = 0;
    for (int kt = 0; kt < NKT; ++kt) {
        float4 nq0, nq1, nb[8];
        const bool pf = (kt + 1 < NKT);
        if (pf) {
            const int kb = (kt + 1) * BK;
            nq0 = *reinterpret_cast<const float4*>(base + qr0 * HH + kb + kf * 4);
            if (q1) nq1 = *reinterpret_cast<const float4*>(base + qr1 * HH + kb + kf * 4);
            #pragma unroll
            for (int j = 0; j < 8; ++j) {
                float4 z = {0.f, 0.f, 0.f, 0.f};
                nb[j] = bvld[j] ? *reinterpret_cast<const float4*>(base + (size_t)growB[j] * HH + kb + kf * 4) : z;
            }
        }
        // compute on buf[cur]
        #pragma unroll
        for (int ks = 0; ks < BK; ks += 32) {
            const int ko = ks + quad * 8;
            bf16x8 a0 = *reinterpret_cast<const bf16x8*>(&sQ[cur][m16][ko]);
            bf16x8 a1 = *reinterpret_cast<const bf16x8*>(&sQ[cur][16 + m16][ko]);
            bf16x8 b0 = *reinterpret_cast<const bf16x8*>(&sB[cur][wave * 32 + m16][ko]);
            bf16x8 b1 = *reinterpret_cast<const bf16x8*>(&sB[cur][wave * 32 + 16 + m16][ko]);
            acc[0][0] = __builtin_amdgcn_mfma_f32_16x16x32_bf16(a0, b0, acc[0][0], 0, 0, 0);
            acc[0][1] = __builtin_amdgcn_mfma_f32_16x16x32_bf16(a0, b1, acc[0][1], 0, 0, 0);
            acc[1][0] = __builtin_amdgcn_mfma_f32_16x16x32_bf16(a1, b0, acc[1][0], 0, 0, 0);
            acc[1][1] = __builtin_amdgcn_mfma_f32_16x16x32_bf16(a1, b1, acc[1][1], 0, 0, 0);
        }
        // convert+write next tile into the other buffer (read last iteration,
        // whose reads completed before the previous barrier -> race-free)
        if (pf) {
            const int nxt = cur ^ 1;
            qn0 += nq0.x*nq0.x + nq0.y*nq0.y + nq0.z*nq0.z + nq0.w*nq0.w;
            uint2 hw;
            hw.x = pk2bf(nq0.x, nq0.y); hw.y = pk2bf(nq0.z, nq0.w);
            *reinterpret_cast<uint2*>(&sQ[nxt][qr0][kf * 4]) = hw;
            if (q1) {
                qn1 += nq1.x*nq1.x + nq1.y*nq1.y + nq1.z*nq1.z + nq1.w*nq1.w;
                hw.x = pk2bf(nq1.x, nq1.y); hw.y = pk2bf(nq1.z, nq1.w);
                *reinterpret_cast<uint2*>(&sQ[nxt][qr1][kf * 4]) = hw;
            }
            #pragma unroll
            for (int j = 0; j < 8; ++j) {
                dnacc[j] += nb[j].x*nb[j].x + nb[j].y*nb[j].y + nb[j].z*nb[j].z + nb[j].w*nb[j].w;
                uint2 w2;
                w2.x = pk2bf(nb[j].x, nb[j].y); w2.y = pk2bf(nb[j].z, nb[j].w);
                *reinterpret_cast<uint2*>(&sB[nxt][rb + 16 * j][kf * 4]) = w2;
            }
        }
        __syncthreads();
        cur ^= 1;
    }

    // ---- norms (one atomic per accumulator, not per load) ----
    atomicAdd(&s_qn2[qr0], qn0);
    if (q1) atomicAdd(&s_qn2[qr1], qn1);
    #pragma unroll
    for (int j = 0; j < 8; ++j)
        if (bvld[j]) atomicAdd(&s_dn2[rb + 16 * j], dnacc[j]);
    __syncthreads();
    if (t < QL) s_qn[t] = sqrtf(s_qn2[t]);
    if (t < BN) s_dn[t] = sqrtf(s_dn2[t]);
    __syncthreads();

    // ---- sims + histogram from C-layout: row(q)=quad*4+reg, col(d)=lane&15 ----
    int cnt[NBINS];
    #pragma unroll
    for (int k = 0; k < NBINS; ++k) cnt[k] = 0;
    #pragma unroll
    for (int mt = 0; mt < 2; ++mt) {
        #pragma unroll
        for (int nt = 0; nt < 2; ++nt) {
            int d = wave * 32 + nt * 16 + m16;
            #pragma unroll
            for (int r = 0; r < 4; ++r) {
                int q = mt * 16 + quad * 4 + r;
                if (q < QL && d < BROWS) {
                    float sim = acc[mt][nt][r] / fmaxf(s_qn[q] * s_dn[d], 1e-8f);
                    int bin = (int)floorf((sim + 1.0f) * 5.5f);  // 11 bins over [-1,1)
                    #pragma unroll
                    for (int k = 0; k < NBINS; ++k) cnt[k] += (bin == k) ? 1 : 0;
                }
            }
        }
    }
    #pragma unroll
    for (int k = 0; k < NBINS; ++k) {
        int v = cnt[k];
        for (int off = 32; off > 0; off >>= 1) v += __shfl_down(v, off, 64);
        if (lane == 0 && v != 0) atomicAdd(&s_hist[k], v);
    }
    __syncthreads();
    if (t < NBINS)
        counts[(((size_t)(l * NBATCH + b)) * DSPLIT + dc) * NBINS + t] = (float)s_hist[t];
}

// ---------------- finalize: cls dot + histogram fold + biases ----------------
__global__ __launch_bounds__(256)
void finalize_kernel(const float* __restrict__ hs,
                     const float* __restrict__ Wh,   // (5,11)
                     const float* __restrict__ bh,   // (5,)
                     const float* __restrict__ Wc,   // (1,838)
                     const float* __restrict__ bc,   // (1,)
                     const float* __restrict__ counts,
                     float* __restrict__ out) {
    const int b = blockIdx.x;
    const int t = threadIdx.x;
    float p = 0.f;

    const float* cls = hs + ((size_t)(12 * NBATCH + b)) * SS * HH;
    for (int j = t; j < HH; j += 256) p += cls[j] * Wc[j];

    if (t < 14 * NBINS) {
        const int l  = t / NBINS;             // all_layers index 0..13
        const int n  = t % NBINS;
        const int lp = (l == 0) ? 0 : l - 1;  // unique-layer index
        float hsum = 0.f;
        #pragma unroll
        for (int dcc = 0; dcc < DSPLIT; ++dcc)
            hsum += counts[(((size_t)lp * NBATCH + b) * DSPLIT + dcc) * NBINS + n];
        float hist = hsum * (1.0f / (float)(QL * DD));
        float coef = 0.f;
        #pragma unroll
        for (int o = 0; o < 5; ++o) coef += Wc[HH + l * 5 + o] * Wh[o * NBINS + n];
        p += hist * coef;
    }

    if (t == 0) {
        float s = bc[0];
        for (int l = 0; l < 14; ++l)
            for (int o = 0; o < 5; ++o) s += Wc[HH + l * 5 + o] * bh[o];
        p += s;
    }

    __shared__ float red[256];
    red[t] = p;
    __syncthreads();
    for (int off = 128; off > 0; off >>= 1) {
        if (t < off) red[t] += red[t + off];
        __syncthreads();
    }
    if (t == 0) out[b] = red[0];
}

extern "C" void kernel_launch(void* const* d_in, const int* in_sizes, int n_in,
                              void* d_out, int out_size, void* d_ws, size_t ws_size,
                              hipStream_t stream) {
    const float* hs = (const float*)d_in[0];
    const float* Wh = (const float*)d_in[1];
    const float* bh = (const float*)d_in[2];
    const float* Wc = (const float*)d_in[3];
    const float* bc = (const float*)d_in[4];
    float* counts = (float*)d_ws;      // 13*16*4*11 floats
    float* out    = (float*)d_out;     // (16,1) fp32

    dim3 g1(NLAYER, NBATCH, DSPLIT);
    gemm_hist_kernel<<<g1, 256, 0, stream>>>(hs, counts);
    finalize_kernel<<<NBATCH, 256, 0, stream>>>(hs, Wh, bh, Wc, bc, counts, out);
}

// Round 3
// 452.628 us; speedup vs baseline: 1.0604x; 1.0476x over previous
//
#include <hip/hip_runtime.h>
#include <math.h>

#define HH    768
#define QL    20
#define SS    512
#define DD    492
#define NBATCH 16
#define NLAYER 13
#define NBINS 11
#define DSPLIT 8
#define BROWS 62           // d-rows per block (8*62=496 >= 492, last block 58 real)
#define BN    64           // padded d-rows per block
#define BK    64
#define NKT   (HH / BK)    // 12 k-tiles
#define BPAD  72           // LDS row length in bf16 (64 + 8 pad)

typedef __attribute__((ext_vector_type(8))) short bf16x8;
typedef __attribute__((ext_vector_type(4))) float f32x4;

__device__ inline unsigned int pk2bf(float a, float b) {
    unsigned int ua = __float_as_uint(a);
    unsigned int ub = __float_as_uint(b);
    ua = (ua + 0x7fffu + ((ua >> 16) & 1u)) >> 16;   // RNE truncate
    ub = (ub + 0x7fffu + ((ub >> 16) & 1u)) >> 16;
    return ua | (ub << 16);
}

// Grid (13,16,8), 256 threads (4 waves). Per block: C(20x62) = Q(20x768)·Dchunk^T
// via mfma_f32_16x16x32_bf16, fp32 norms, fused histogram. Partial counts -> ws.
// v3: DSPLIT=8 / BN=64 -> LDS 28KB, 4 blocks/CU, 1664 blocks (tail-friendly);
// each wave owns 16 d-rows (acc[2][1]); double-buffered, 1 barrier per k-tile.
__global__ __launch_bounds__(256, 4)
void gemm_hist_kernel(const float* __restrict__ hs, float* __restrict__ counts) {
    const int l = blockIdx.x, b = blockIdx.y, dc = blockIdx.z;
    const float* __restrict__ base = hs + (size_t)(l * NBATCH + b) * SS * HH;
    const int t = threadIdx.x;
    const int wave = t >> 6, lane = t & 63;
    const int quad = lane >> 4, m16 = lane & 15;
    const int valid = (dc == DSPLIT - 1) ? (DD - (DSPLIT - 1) * BROWS) : BROWS; // 62 or 58

    __shared__ unsigned short sQ[2][32][BPAD];   // 9.2 KB  (rows 20..31 zero)
    __shared__ unsigned short sB[2][BN][BPAD];   // 18.4 KB
    __shared__ float s_qn2[QL], s_qn[QL];
    __shared__ float s_dn2[BN], s_dn[BN];
    __shared__ int   s_hist[NBINS];

    // ---- one-time init ----
    if (t < QL) s_qn2[t] = 0.f;
    if (t < BN) s_dn2[t] = 0.f;
    if (t < NBINS) s_hist[t] = 0;
    for (int i = t; i < 2 * 12 * BPAD; i += 256) {   // zero sQ pad rows (both bufs)
        int bufi = i / (12 * BPAD);
        int rem  = i - bufi * (12 * BPAD);
        sQ[bufi][20 + rem / BPAD][rem % BPAD] = 0;
    }

    // ---- fixed per-thread staging geometry (column advances with kt) ----
    const int  kf  = t & 15;            // float4-column within k-tile
    const int  qr0 = t >> 4;            // Q rows 0..15 (all threads)
    const bool q1  = (t < 64);          // wave 0 also stages Q rows 16..19
    const int  qr1 = 16 + (t >> 4);
    const int  rb  = t >> 4;            // B rows rb + 16j, j=0..3
    int  growB[4];
    bool bvld[4];
    #pragma unroll
    for (int j = 0; j < 4; ++j) {
        int row  = rb + 16 * j;
        bvld[j]  = (row < valid);
        growB[j] = QL + dc * BROWS + (row < valid ? row : valid - 1);
    }

    float qn0 = 0.f, qn1 = 0.f;
    float dnacc[4];
    #pragma unroll
    for (int j = 0; j < 4; ++j) dnacc[j] = 0.f;
    f32x4 acc[2] = {{0,0,0,0},{0,0,0,0}};

    // ---- prologue: load k-tile 0, convert+write buffer 0 ----
    {
        float4 pq0, pq1, pb[4];
        pq0 = *reinterpret_cast<const float4*>(base + qr0 * HH + kf * 4);
        if (q1) pq1 = *reinterpret_cast<const float4*>(base + qr1 * HH + kf * 4);
        #pragma unroll
        for (int j = 0; j < 4; ++j)
            pb[j] = *reinterpret_cast<const float4*>(base + (size_t)growB[j] * HH + kf * 4);
        qn0 += pq0.x*pq0.x + pq0.y*pq0.y + pq0.z*pq0.z + pq0.w*pq0.w;
        uint2 hw;
        hw.x = pk2bf(pq0.x, pq0.y); hw.y = pk2bf(pq0.z, pq0.w);
        *reinterpret_cast<uint2*>(&sQ[0][qr0][kf * 4]) = hw;
        if (q1) {
            qn1 += pq1.x*pq1.x + pq1.y*pq1.y + pq1.z*pq1.z + pq1.w*pq1.w;
            hw.x = pk2bf(pq1.x, pq1.y); hw.y = pk2bf(pq1.z, pq1.w);
            *reinterpret_cast<uint2*>(&sQ[0][qr1][kf * 4]) = hw;
        }
        #pragma unroll
        for (int j = 0; j < 4; ++j) {
            if (bvld[j]) dnacc[j] += pb[j].x*pb[j].x + pb[j].y*pb[j].y + pb[j].z*pb[j].z + pb[j].w*pb[j].w;
            uint2 w2;
            w2.x = pk2bf(pb[j].x, pb[j].y); w2.y = pk2bf(pb[j].z, pb[j].w);
            *reinterpret_cast<uint2*>(&sB[0][rb + 16 * j][kf * 4]) = w2;
        }
    }
    __syncthreads();

    // ---- main loop: one barrier per k-tile; prefetch kt+1 over MFMA(kt) ----
    int cur = 0;
    for (int kt = 0; kt < NKT; ++kt) {
        float4 nq0, nq1, nb[4];
        const bool pf = (kt + 1 < NKT);
        if (pf) {
            const int kb = (kt + 1) * BK;
            nq0 = *reinterpret_cast<const float4*>(base + qr0 * HH + kb + kf * 4);
            if (q1) nq1 = *reinterpret_cast<const float4*>(base + qr1 * HH + kb + kf * 4);
            #pragma unroll
            for (int j = 0; j < 4; ++j)
                nb[j] = *reinterpret_cast<const float4*>(base + (size_t)growB[j] * HH + kb + kf * 4);
        }
        // compute on buf[cur]: wave owns d-rows wave*16..wave*16+15
        #pragma unroll
        for (int ks = 0; ks < BK; ks += 32) {
            const int ko = ks + quad * 8;
            bf16x8 a0 = *reinterpret_cast<const bf16x8*>(&sQ[cur][m16][ko]);
            bf16x8 a1 = *reinterpret_cast<const bf16x8*>(&sQ[cur][16 + m16][ko]);
            bf16x8 bb = *reinterpret_cast<const bf16x8*>(&sB[cur][wave * 16 + m16][ko]);
            acc[0] = __builtin_amdgcn_mfma_f32_16x16x32_bf16(a0, bb, acc[0], 0, 0, 0);
            acc[1] = __builtin_amdgcn_mfma_f32_16x16x32_bf16(a1, bb, acc[1], 0, 0, 0);
        }
        // convert+write next tile into the other buffer (race-free: last
        // iteration's reads of that buffer completed before previous barrier)
        if (pf) {
            const int nxt = cur ^ 1;
            qn0 += nq0.x*nq0.x + nq0.y*nq0.y + nq0.z*nq0.z + nq0.w*nq0.w;
            uint2 hw;
            hw.x = pk2bf(nq0.x, nq0.y); hw.y = pk2bf(nq0.z, nq0.w);
            *reinterpret_cast<uint2*>(&sQ[nxt][qr0][kf * 4]) = hw;
            if (q1) {
                qn1 += nq1.x*nq1.x + nq1.y*nq1.y + nq1.z*nq1.z + nq1.w*nq1.w;
                hw.x = pk2bf(nq1.x, nq1.y); hw.y = pk2bf(nq1.z, nq1.w);
                *reinterpret_cast<uint2*>(&sQ[nxt][qr1][kf * 4]) = hw;
            }
            #pragma unroll
            for (int j = 0; j < 4; ++j) {
                if (bvld[j]) dnacc[j] += nb[j].x*nb[j].x + nb[j].y*nb[j].y + nb[j].z*nb[j].z + nb[j].w*nb[j].w;
                uint2 w2;
                w2.x = pk2bf(nb[j].x, nb[j].y); w2.y = pk2bf(nb[j].z, nb[j].w);
                *reinterpret_cast<uint2*>(&sB[nxt][rb + 16 * j][kf * 4]) = w2;
            }
        }
        __syncthreads();
        cur ^= 1;
    }

    // ---- norms (one atomic per accumulator) ----
    atomicAdd(&s_qn2[qr0], qn0);
    if (q1) atomicAdd(&s_qn2[qr1], qn1);
    #pragma unroll
    for (int j = 0; j < 4; ++j)
        if (bvld[j]) atomicAdd(&s_dn2[rb + 16 * j], dnacc[j]);
    __syncthreads();
    if (t < QL) s_qn[t] = sqrtf(s_qn2[t]);
    if (t < BN) s_dn[t] = sqrtf(s_dn2[t]);
    __syncthreads();

    // ---- sims + histogram from C-layout: row(q)=quad*4+reg, col(d)=lane&15 ----
    int cnt[NBINS];
    #pragma unroll
    for (int k = 0; k < NBINS; ++k) cnt[k] = 0;
    {
        const int d = wave * 16 + m16;
        #pragma unroll
        for (int mt = 0; mt < 2; ++mt) {
            #pragma unroll
            for (int r = 0; r < 4; ++r) {
                int q = mt * 16 + quad * 4 + r;
                if (q < QL && d < valid) {
                    float sim = acc[mt][r] / fmaxf(s_qn[q] * s_dn[d], 1e-8f);
                    int bin = (int)floorf((sim + 1.0f) * 5.5f);  // 11 bins over [-1,1)
                    #pragma unroll
                    for (int k = 0; k < NBINS; ++k) cnt[k] += (bin == k) ? 1 : 0;
                }
            }
        }
    }
    #pragma unroll
    for (int k = 0; k < NBINS; ++k) {
        int v = cnt[k];
        for (int off = 32; off > 0; off >>= 1) v += __shfl_down(v, off, 64);
        if (lane == 0 && v != 0) atomicAdd(&s_hist[k], v);
    }
    __syncthreads();
    if (t < NBINS)
        counts[(((size_t)(l * NBATCH + b)) * DSPLIT + dc) * NBINS + t] = (float)s_hist[t];
}

// ---------------- finalize: cls dot + histogram fold + biases ----------------
__global__ __launch_bounds__(256)
void finalize_kernel(const float* __restrict__ hs,
                     const float* __restrict__ Wh,   // (5,11)
                     const float* __restrict__ bh,   // (5,)
                     const float* __restrict__ Wc,   // (1,838)
                     const float* __restrict__ bc,   // (1,)
                     const float* __restrict__ counts,
                     float* __restrict__ out) {
    const int b = blockIdx.x;
    const int t = threadIdx.x;
    float p = 0.f;

    const float* cls = hs + ((size_t)(12 * NBATCH + b)) * SS * HH;
    for (int j = t; j < HH; j += 256) p += cls[j] * Wc[j];

    if (t < 14 * NBINS) {
        const int l  = t / NBINS;             // all_layers index 0..13
        const int n  = t % NBINS;
        const int lp = (l == 0) ? 0 : l - 1;  // unique-layer index
        float hsum = 0.f;
        #pragma unroll
        for (int dcc = 0; dcc < DSPLIT; ++dcc)
            hsum += counts[(((size_t)lp * NBATCH + b) * DSPLIT + dcc) * NBINS + n];
        float hist = hsum * (1.0f / (float)(QL * DD));
        float coef = 0.f;
        #pragma unroll
        for (int o = 0; o < 5; ++o) coef += Wc[HH + l * 5 + o] * Wh[o * NBINS + n];
        p += hist * coef;
    }

    if (t == 0) {
        float s = bc[0];
        for (int l = 0; l < 14; ++l)
            for (int o = 0; o < 5; ++o) s += Wc[HH + l * 5 + o] * bh[o];
        p += s;
    }

    __shared__ float red[256];
    red[t] = p;
    __syncthreads();
    for (int off = 128; off > 0; off >>= 1) {
        if (t < off) red[t] += red[t + off];
        __syncthreads();
    }
    if (t == 0) out[b] = red[0];
}

extern "C" void kernel_launch(void* const* d_in, const int* in_sizes, int n_in,
                              void* d_out, int out_size, void* d_ws, size_t ws_size,
                              hipStream_t stream) {
    const float* hs = (const float*)d_in[0];
    const float* Wh = (const float*)d_in[1];
    const float* bh = (const float*)d_in[2];
    const float* Wc = (const float*)d_in[3];
    const float* bc = (const float*)d_in[4];
    float* counts = (float*)d_ws;      // 13*16*8*11 floats
    float* out    = (float*)d_out;     // (16,1) fp32

    dim3 g1(NLAYER, NBATCH, DSPLIT);
    gemm_hist_kernel<<<g1, 256, 0, stream>>>(hs, counts);
    finalize_kernel<<<NBATCH, 256, 0, stream>>>(hs, Wh, bh, Wc, bc, counts, out);
}